// Round 3
// baseline (260.462 us; speedup 1.0000x reference)
//
#include <hip/hip_runtime.h>
#include <hip/hip_bf16.h>

// ---- vector types (ext_vector for [] indexing; avoid HIP name collisions) ----
typedef __attribute__((ext_vector_type(8))) short short8v;      // 8 bf16 (4 VGPR) MFMA frag
typedef __attribute__((ext_vector_type(4))) float floatx4;      // MFMA accum
typedef __attribute__((ext_vector_type(4))) unsigned short ushortx4;

// RNE f32->bf16 via the official cast (compiler can fuse pairs into v_cvt_pk_bf16_f32)
__device__ __forceinline__ unsigned short f2bf(float f){
  __hip_bfloat16 h = __float2bfloat16(f);
  unsigned short u;
  __builtin_memcpy(&u, &h, 2);
  return u;
}

__device__ __forceinline__ void gload_lds16(const void* g, void* l){
  __builtin_amdgcn_global_load_lds((const __attribute__((address_space(1))) void*)g,
                                   (__attribute__((address_space(3))) void*)l, 16, 0, 0);
}

// ---- f32 -> bf16 convert, vectorized (G13) ----
__global__ __launch_bounds__(256) void cvt4(const floatx4* __restrict__ s,
                                            ushortx4* __restrict__ d, int n4){
  int i = blockIdx.x * 256 + threadIdx.x;
  if(i < n4){
    floatx4 v = s[i];
    ushortx4 o;
    #pragma unroll
    for(int j = 0; j < 4; ++j) o[j] = f2bf(v[j]);
    d[i] = o;
  }
}

// ---- 2D RoPE cos/sin table: cs[p*64+d] = (cos theta, sin theta) ----
__global__ __launch_bounds__(256) void cs_init(float2* __restrict__ cs){
  int i = blockIdx.x * 256 + threadIdx.x;     // 0..65535
  int p = i >> 6, d = i & 63;
  int y = p >> 5, x = p & 31;
  int dd = d & 31;
  float ifr = powf(10000.0f, -(float)dd * (1.0f / 32.0f));
  float th = (float)(d < 32 ? y : x) * ifr;
  cs[i].x = cosf(th);
  cs[i].y = sinf(th);
}

// ---- GEMM C = A * B^T  (A: M x K bf16 row-major, B: N x K bf16 row-major) ----
// 128x128 tile, BK=32, 4 waves each 64x64 (4x4 frags of 16x16x32 bf16 MFMA).
// EPI=0: write f32 C.  EPI=1: QKV epilogue (RoPE on q/k, q*=0.125*log2e, V^T).
template<int EPI>
__global__ __launch_bounds__(256) void gemm_bt(
    const unsigned short* __restrict__ A,
    const unsigned short* __restrict__ B,
    int K, int N,
    float* __restrict__ Cf,
    const float2* __restrict__ cs,
    unsigned short* __restrict__ qw,
    unsigned short* __restrict__ kw,
    unsigned short* __restrict__ vtw)
{
  __shared__ unsigned short Al[128 * 32];
  __shared__ unsigned short Bl[128 * 32];
  const int tid = threadIdx.x;
  const int w = tid >> 6, lane = tid & 63;
  const int g = lane >> 4, c0 = lane & 15;
  const int wr = w >> 1, wc = w & 1;
  const size_t m0 = (size_t)blockIdx.y * 128;
  const size_t n0 = (size_t)blockIdx.x * 128;

  floatx4 acc[4][4] = {};

  for(int k0 = 0; k0 < K; k0 += 32){
    #pragma unroll
    for(int q = 0; q < 2; ++q){
      int ci = q * 256 + tid;
      int row = ci >> 2, ko = (ci & 3) << 3;
      gload_lds16(A + (m0 + row) * K + k0 + ko, Al + (size_t)(q * 256 + w * 64) * 8);
      gload_lds16(B + (n0 + row) * K + k0 + ko, Bl + (size_t)(q * 256 + w * 64) * 8);
    }
    __syncthreads();
    short8v am[4], bn[4];
    #pragma unroll
    for(int mf = 0; mf < 4; ++mf)
      am[mf] = *(const short8v*)(Al + (wr * 64 + mf * 16 + c0) * 32 + g * 8);
    #pragma unroll
    for(int nf = 0; nf < 4; ++nf)
      bn[nf] = *(const short8v*)(Bl + (wc * 64 + nf * 16 + c0) * 32 + g * 8);
    #pragma unroll
    for(int mf = 0; mf < 4; ++mf)
      #pragma unroll
      for(int nf = 0; nf < 4; ++nf)
        acc[mf][nf] = __builtin_amdgcn_mfma_f32_16x16x32_bf16(am[mf], bn[nf], acc[mf][nf], 0, 0, 0);
    __syncthreads();
  }

  // C-layout: col = lane&15 (=c0), row = (lane>>4)*4 + r  [m89-verified]
  if(EPI == 0){
    #pragma unroll
    for(int mf = 0; mf < 4; ++mf){
      size_t mrow = m0 + wr * 64 + mf * 16 + g * 4;
      #pragma unroll
      for(int nf = 0; nf < 4; ++nf){
        size_t n = n0 + wc * 64 + nf * 16 + c0;
        #pragma unroll
        for(int r = 0; r < 4; ++r)
          Cf[(mrow + r) * N + n] = acc[mf][nf][r];
      }
    }
  } else {
    int t = (int)(n0 >> 6) + wc;          // 0..47
    int sect = t % 3, hh = t / 3;         // 0=q,1=k,2=v ; head
    if(sect == 2){
      // V -> V^T [bh][64][1024]; pack 4 consecutive n-positions (regs) per store
      #pragma unroll
      for(int mf = 0; mf < 4; ++mf){
        size_t m = m0 + wr * 64 + mf * 16 + g * 4;
        int b = (int)(m >> 10); int p = (int)(m & 1023);
        #pragma unroll
        for(int nf = 0; nf < 4; ++nf){
          int d = nf * 16 + c0;
          ushortx4 pk;
          #pragma unroll
          for(int r = 0; r < 4; ++r) pk[r] = f2bf(acc[mf][nf][r]);
          *(ushortx4*)(vtw + ((size_t)(b * 16 + hh) * 64 + d) * 1024 + p) = pk;
        }
      }
    } else {
      // RoPE: pairs (d, d+32) live in frags (nf, nf+2) of the same thread
      unsigned short* dst = (sect == 0) ? qw : kw;
      // fold attention scale AND log2(e) (exp2-domain softmax) into Q
      const float qs = (sect == 0) ? 0.18033688011112042f : 1.0f;
      #pragma unroll
      for(int mf = 0; mf < 4; ++mf){
        #pragma unroll
        for(int r = 0; r < 4; ++r){
          size_t m = m0 + wr * 64 + mf * 16 + g * 4 + r;
          int b = (int)(m >> 10); int p = (int)(m & 1023);
          const float2* csr = cs + (size_t)p * 64;
          unsigned short* orow = dst + ((size_t)(b * 16 + hh) * 1024 + p) * 64;
          #pragma unroll
          for(int nf = 0; nf < 2; ++nf){
            int d = nf * 16 + c0;
            float x1 = acc[mf][nf][r], x2 = acc[mf][nf + 2][r];
            float2 cc1 = csr[d], cc2 = csr[d + 32];
            orow[d]      = f2bf((x1 * cc1.x - x2 * cc1.y) * qs);
            orow[d + 32] = f2bf((x2 * cc2.x + x1 * cc2.y) * qs);
          }
        }
      }
    }
  }
}

// ---- flash attention v3: 1024 blocks (XCD-swizzled), 4 waves x 32 q-rows ----
// All 8 q-tiles of one bh run on the SAME XCD (K/V stay L2-resident: ~1.25MB
// working set per XCD vs 4MB L2). exp2-domain softmax (log2e folded into Q).
// No barriers (P-LDS wave-private). l-reduction deferred to kernel end.
__global__ __launch_bounds__(256) void attn_kernel(
    const unsigned short* __restrict__ qw,
    const unsigned short* __restrict__ kw,
    const unsigned short* __restrict__ vtw,
    unsigned short* __restrict__ ow)
{
  __shared__ unsigned short Plds[4 * 2048];   // 4KB per wave: [q=32][kv=64] bf16
  const int tid = threadIdx.x;
  const int w = tid >> 6, lane = tid & 63;
  const int g = lane >> 4, c0 = lane & 15;
  // XCD-aware decode: block b -> XCD b%8; give each XCD whole bh's (16 of them)
  const int bb = blockIdx.x;
  const int xcd = bb & 7, slot = bb >> 3;
  const int bh = xcd + ((slot >> 3) << 3);
  const int qt = slot & 7;
  const size_t bhoff = (size_t)bh * 1024 * 64;
  const unsigned short* Qb = qw + bhoff;
  const unsigned short* Kb = kw + bhoff;
  const unsigned short* Vb = vtw + bhoff;
  const int q0 = qt * 128 + w * 32;
  char* Pw = (char*)(Plds + w * 2048);

  // Q as B-operand, hoisted: [qf][chain]  (col=c0 -> q0+qf*16+c0 ; k=d=g*8+j+32i)
  short8v bq[2][2];
  #pragma unroll
  for(int qf = 0; qf < 2; ++qf)
    #pragma unroll
    for(int i = 0; i < 2; ++i)
      bq[qf][i] = *(const short8v*)(Qb + (size_t)(q0 + qf * 16 + c0) * 64 + g * 8 + i * 32);

  floatx4 o[2][4] = {};                 // [qf(=mf)][nf]; row=q=mf*16+g*4+r, col=d=nf*16+c0
  float m_run[2] = {-1e30f, -1e30f};
  float l_part[2] = {0.0f, 0.0f};       // per-thread partial (xor-reduced at end)

  for(int kv0 = 0; kv0 < 1024; kv0 += 64){
    // S^T tile (64 kv x 32 q), log2-domain: A = K rows, chained over d
    floatx4 st[4][2];
    #pragma unroll
    for(int kf = 0; kf < 4; ++kf){
      const unsigned short* kr = Kb + (size_t)(kv0 + kf * 16 + c0) * 64 + g * 8;
      short8v ka0 = *(const short8v*)kr;
      short8v ka1 = *(const short8v*)(kr + 32);
      #pragma unroll
      for(int qf = 0; qf < 2; ++qf){
        floatx4 z = {};
        z = __builtin_amdgcn_mfma_f32_16x16x32_bf16(ka0, bq[qf][0], z, 0, 0, 0);
        st[kf][qf] = __builtin_amdgcn_mfma_f32_16x16x32_bf16(ka1, bq[qf][1], z, 0, 0, 0);
      }
    }
    // per-q-column max (thread holds 16 kv values per qf; finish via xor 16,32)
    float vmax[2];
    #pragma unroll
    for(int qf = 0; qf < 2; ++qf){
      float vm = -1e30f;
      #pragma unroll
      for(int kf = 0; kf < 4; ++kf)
        #pragma unroll
        for(int r = 0; r < 4; ++r) vm = fmaxf(vm, st[kf][qf][r]);
      vm = fmaxf(vm, __shfl_xor(vm, 16));
      vm = fmaxf(vm, __shfl_xor(vm, 32));
      vmax[qf] = vm;
    }
    // T13 defer-max: only rescale when max grew by > 8 (values bounded by 2^8)
    if(!__all(vmax[0] <= m_run[0] + 8.0f && vmax[1] <= m_run[1] + 8.0f)){
      #pragma unroll
      for(int qf = 0; qf < 2; ++qf){
        float m_new = fmaxf(m_run[qf], vmax[qf]);
        float sc = __builtin_amdgcn_exp2f(m_run[qf] - m_new);
        l_part[qf] *= sc;
        m_run[qf] = m_new;
        float f0 = __shfl(sc, g * 4 + 0);
        float f1 = __shfl(sc, g * 4 + 1);
        float f2 = __shfl(sc, g * 4 + 2);
        float f3 = __shfl(sc, g * 4 + 3);
        #pragma unroll
        for(int nf = 0; nf < 4; ++nf){
          o[qf][nf][0] *= f0; o[qf][nf][1] *= f1; o[qf][nf][2] *= f2; o[qf][nf][3] *= f3;
        }
      }
    }
    // P = exp2(S - m), bf16; per-thread partial row-sums only (reduce at end)
    #pragma unroll
    for(int qf = 0; qf < 2; ++qf){
      float ps = 0.0f;
      #pragma unroll
      for(int kf = 0; kf < 4; ++kf){
        ushortx4 pk;
        #pragma unroll
        for(int r = 0; r < 4; ++r){
          float e = __builtin_amdgcn_exp2f(st[kf][qf][r] - m_run[qf]);
          ps += e;
          pk[r] = f2bf(e);
        }
        // P -> LDS [q=qf*16+c0][kv=kf*16+g*4], XOR-swizzled (G4)
        int byo = (qf << 11) + (c0 << 7) + (kf << 5) + (g << 3);
        byo ^= (c0 & 7) << 4;
        *(ushortx4*)(Pw + byo) = pk;
      }
      l_part[qf] += ps;
    }
    // V^T loads issued here (st dead -> low VGPR peak; latency hides under pa reads)
    short8v vv[4][2];
    #pragma unroll
    for(int nf = 0; nf < 4; ++nf){
      const unsigned short* vr = Vb + (size_t)(nf * 16 + c0) * 1024 + kv0 + g * 8;
      vv[nf][0] = *(const short8v*)vr;
      vv[nf][1] = *(const short8v*)(vr + 32);
    }
    // P as A-operand: row=q=mf*16+c0, k=kv=g*8+j(+32i)  (wave-private: no barrier)
    short8v pa[2][2];
    #pragma unroll
    for(int mf = 0; mf < 2; ++mf)
      #pragma unroll
      for(int i = 0; i < 2; ++i){
        int byo = (mf << 11) + (c0 << 7) + (i << 6) + (g << 4);
        byo ^= (c0 & 7) << 4;
        pa[mf][i] = *(const short8v*)(Pw + byo);
      }
    #pragma unroll
    for(int nf = 0; nf < 4; ++nf){
      #pragma unroll
      for(int mf = 0; mf < 2; ++mf){
        o[mf][nf] = __builtin_amdgcn_mfma_f32_16x16x32_bf16(pa[mf][0], vv[nf][0], o[mf][nf], 0, 0, 0);
        o[mf][nf] = __builtin_amdgcn_mfma_f32_16x16x32_bf16(pa[mf][1], vv[nf][1], o[mf][nf], 0, 0, 0);
      }
    }
  }

  const int b = bh >> 4, hh = bh & 15;
  #pragma unroll
  for(int mf = 0; mf < 2; ++mf){
    l_part[mf] += __shfl_xor(l_part[mf], 16);
    l_part[mf] += __shfl_xor(l_part[mf], 32);
    float i0 = 1.0f / __shfl(l_part[mf], g * 4 + 0);
    float i1 = 1.0f / __shfl(l_part[mf], g * 4 + 1);
    float i2 = 1.0f / __shfl(l_part[mf], g * 4 + 2);
    float i3 = 1.0f / __shfl(l_part[mf], g * 4 + 3);
    #pragma unroll
    for(int nf = 0; nf < 4; ++nf){
      o[mf][nf][0] *= i0; o[mf][nf][1] *= i1; o[mf][nf][2] *= i2; o[mf][nf][3] *= i3;
      #pragma unroll
      for(int r = 0; r < 4; ++r){
        size_t row = (size_t)b * 1024 + q0 + mf * 16 + g * 4 + r;
        ow[row * 1024 + hh * 64 + nf * 16 + c0] = f2bf(o[mf][nf][r]);
      }
    }
  }
}

// ---- workspace layout (bytes) ----
//   bfT    @ 0         16,777,216   tensor bf16 (8192x1024)
//   bfWq   @ 16777216   6,291,456   w_qkv bf16 (3072x1024)
//   bfWp   @ 23068672   2,097,152   w_proj bf16 (1024x1024)
//   cs     @ 25165824     524,288   RoPE table float2 (1024x64)
//   qw     @ 25690112  16,777,216   Q rope'd*scale bf16 [bh][1024][64]
//   kw     @ 42467328  16,777,216   K rope'd bf16 [bh][1024][64]
//   vtw    @ 59244544  16,777,216   V^T bf16 [bh][64][1024]
//   ow     @ 76021760  16,777,216   attn out bf16 [b*n][c]

extern "C" void kernel_launch(void* const* d_in, const int* in_sizes, int n_in,
                              void* d_out, int out_size, void* d_ws, size_t ws_size,
                              hipStream_t stream){
  const float* tensor = (const float*)d_in[0];
  const float* w_qkv  = (const float*)d_in[1];
  const float* w_proj = (const float*)d_in[2];
  char* ws = (char*)d_ws;
  unsigned short* bfT  = (unsigned short*)(ws);
  unsigned short* bfWq = (unsigned short*)(ws + 16777216);
  unsigned short* bfWp = (unsigned short*)(ws + 23068672);
  float2*         cs   = (float2*)        (ws + 25165824);
  unsigned short* qw   = (unsigned short*)(ws + 25690112);
  unsigned short* kw   = (unsigned short*)(ws + 42467328);
  unsigned short* vtw  = (unsigned short*)(ws + 59244544);
  unsigned short* owp  = (unsigned short*)(ws + 76021760);

  cvt4<<<8192, 256, 0, stream>>>((const floatx4*)tensor, (ushortx4*)bfT, 2097152);
  cvt4<<<3072, 256, 0, stream>>>((const floatx4*)w_qkv,  (ushortx4*)bfWq, 786432);
  cvt4<<<1024, 256, 0, stream>>>((const floatx4*)w_proj, (ushortx4*)bfWp, 262144);
  cs_init<<<256, 256, 0, stream>>>(cs);

  // QKV: M=8192, N=3072, K=1024 ; fused RoPE epilogue
  gemm_bt<1><<<dim3(24, 64), 256, 0, stream>>>(bfT, bfWq, 1024, 3072,
                                               nullptr, cs, qw, kw, vtw);
  // attention: 1024 blocks, XCD-swizzled decode inside the kernel
  attn_kernel<<<1024, 256, 0, stream>>>(qw, kw, vtw, owp);
  // proj: M=8192, N=1024, K=1024 ; f32 out
  gemm_bt<0><<<dim3(8, 64), 256, 0, stream>>>(owp, bfWp, 1024, 1024,
                                              (float*)d_out, nullptr, nullptr, nullptr, nullptr);
}

// Round 5
// 185.305 us; speedup vs baseline: 1.4056x; 1.4056x over previous
//
#include <hip/hip_runtime.h>

// ---- vector types (ext_vector for [] indexing; avoid HIP name collisions) ----
typedef __attribute__((ext_vector_type(8))) short short8v;      // 8 bf16 (4 VGPR) MFMA frag
typedef __attribute__((ext_vector_type(4))) float floatx4;      // MFMA accum
typedef __attribute__((ext_vector_type(4))) unsigned short ushortx4;

// RNE f32->bf16, 3 VALU ops (values are finite; no NaN path needed)
__device__ __forceinline__ unsigned short f2bf(float f){
  unsigned int u = __float_as_uint(f);
  u += 0x7fffu + ((u >> 16) & 1u);
  return (unsigned short)(u >> 16);
}

__device__ __forceinline__ void gload_lds16(const void* g, void* l){
  __builtin_amdgcn_global_load_lds((const __attribute__((address_space(1))) void*)g,
                                   (__attribute__((address_space(3))) void*)l, 16, 0, 0);
}

// ---- f32 -> bf16 convert, vectorized (G13) ----
__global__ __launch_bounds__(256) void cvt4(const floatx4* __restrict__ s,
                                            ushortx4* __restrict__ d, int n4){
  int i = blockIdx.x * 256 + threadIdx.x;
  if(i < n4){
    floatx4 v = s[i];
    ushortx4 o;
    #pragma unroll
    for(int j = 0; j < 4; ++j) o[j] = f2bf(v[j]);
    d[i] = o;
  }
}

// ---- 2D RoPE cos/sin table: cs[p*64+d] = (cos theta, sin theta) ----
__global__ __launch_bounds__(256) void cs_init(float2* __restrict__ cs){
  int i = blockIdx.x * 256 + threadIdx.x;     // 0..65535
  int p = i >> 6, d = i & 63;
  int y = p >> 5, x = p & 31;
  int dd = d & 31;
  float ifr = powf(10000.0f, -(float)dd * (1.0f / 32.0f));
  float th = (float)(d < 32 ? y : x) * ifr;
  cs[i].x = cosf(th);
  cs[i].y = sinf(th);
}

// ---- GEMM C = A * B^T  (A: M x K bf16 row-major, B: N x K bf16 row-major) ----
// 128x128 tile, BK=32, 4 waves each 64x64 (4x4 frags of 16x16x32 bf16 MFMA).
// EPI=0: write f32 C.  EPI=1: QKV epilogue (RoPE on q/k, q*=0.125*log2e, V^T).
template<int EPI>
__global__ __launch_bounds__(256) void gemm_bt(
    const unsigned short* __restrict__ A,
    const unsigned short* __restrict__ B,
    int K, int N,
    float* __restrict__ Cf,
    const float2* __restrict__ cs,
    unsigned short* __restrict__ qw,
    unsigned short* __restrict__ kw,
    unsigned short* __restrict__ vtw)
{
  __shared__ unsigned short Al[128 * 32];
  __shared__ unsigned short Bl[128 * 32];
  const int tid = threadIdx.x;
  const int w = tid >> 6, lane = tid & 63;
  const int g = lane >> 4, c0 = lane & 15;
  const int wr = w >> 1, wc = w & 1;
  const size_t m0 = (size_t)blockIdx.y * 128;
  const size_t n0 = (size_t)blockIdx.x * 128;

  floatx4 acc[4][4] = {};

  for(int k0 = 0; k0 < K; k0 += 32){
    #pragma unroll
    for(int q = 0; q < 2; ++q){
      int ci = q * 256 + tid;
      int row = ci >> 2, ko = (ci & 3) << 3;
      gload_lds16(A + (m0 + row) * K + k0 + ko, Al + (size_t)(q * 256 + w * 64) * 8);
      gload_lds16(B + (n0 + row) * K + k0 + ko, Bl + (size_t)(q * 256 + w * 64) * 8);
    }
    __syncthreads();
    short8v am[4], bn[4];
    #pragma unroll
    for(int mf = 0; mf < 4; ++mf)
      am[mf] = *(const short8v*)(Al + (wr * 64 + mf * 16 + c0) * 32 + g * 8);
    #pragma unroll
    for(int nf = 0; nf < 4; ++nf)
      bn[nf] = *(const short8v*)(Bl + (wc * 64 + nf * 16 + c0) * 32 + g * 8);
    #pragma unroll
    for(int mf = 0; mf < 4; ++mf)
      #pragma unroll
      for(int nf = 0; nf < 4; ++nf)
        acc[mf][nf] = __builtin_amdgcn_mfma_f32_16x16x32_bf16(am[mf], bn[nf], acc[mf][nf], 0, 0, 0);
    __syncthreads();
  }

  // C-layout: col = lane&15 (=c0), row = (lane>>4)*4 + r  [m89-verified]
  if(EPI == 0){
    #pragma unroll
    for(int mf = 0; mf < 4; ++mf){
      size_t mrow = m0 + wr * 64 + mf * 16 + g * 4;
      #pragma unroll
      for(int nf = 0; nf < 4; ++nf){
        size_t n = n0 + wc * 64 + nf * 16 + c0;
        #pragma unroll
        for(int r = 0; r < 4; ++r)
          Cf[(mrow + r) * N + n] = acc[mf][nf][r];
      }
    }
  } else {
    int t = (int)(n0 >> 6) + wc;          // 0..47
    int sect = t % 3, hh = t / 3;         // 0=q,1=k,2=v ; head
    if(sect == 2){
      // V -> V^T [bh][64][1024]; pack 4 consecutive n-positions (regs) per store
      #pragma unroll
      for(int mf = 0; mf < 4; ++mf){
        size_t m = m0 + wr * 64 + mf * 16 + g * 4;
        int b = (int)(m >> 10); int p = (int)(m & 1023);
        #pragma unroll
        for(int nf = 0; nf < 4; ++nf){
          int d = nf * 16 + c0;
          ushortx4 pk;
          #pragma unroll
          for(int r = 0; r < 4; ++r) pk[r] = f2bf(acc[mf][nf][r]);
          *(ushortx4*)(vtw + ((size_t)(b * 16 + hh) * 64 + d) * 1024 + p) = pk;
        }
      }
    } else {
      // RoPE: pairs (d, d+32) live in frags (nf, nf+2) of the same thread
      unsigned short* dst = (sect == 0) ? qw : kw;
      // fold attention scale AND log2(e) (exp2-domain softmax) into Q
      const float qs = (sect == 0) ? 0.18033688011112042f : 1.0f;
      #pragma unroll
      for(int mf = 0; mf < 4; ++mf){
        #pragma unroll
        for(int r = 0; r < 4; ++r){
          size_t m = m0 + wr * 64 + mf * 16 + g * 4 + r;
          int b = (int)(m >> 10); int p = (int)(m & 1023);
          const float2* csr = cs + (size_t)p * 64;
          unsigned short* orow = dst + ((size_t)(b * 16 + hh) * 1024 + p) * 64;
          #pragma unroll
          for(int nf = 0; nf < 2; ++nf){
            int d = nf * 16 + c0;
            float x1 = acc[mf][nf][r], x2 = acc[mf][nf + 2][r];
            float2 cc1 = csr[d], cc2 = csr[d + 32];
            orow[d]      = f2bf((x1 * cc1.x - x2 * cc1.y) * qs);
            orow[d + 32] = f2bf((x2 * cc2.x + x1 * cc2.y) * qs);
          }
        }
      }
    }
  }
}

// ---- flash attention v4b: 512 blocks x 512 thr (8 waves, 32 q-rows each) ----
// K/V tiles staged in LDS (shared by 8 waves), double-buffered, prefetched one
// iteration ahead via global_load_lds (T3 minimum 2-phase). XOR-swizzled K/V
// LDS layout (G4 / rule #21: linear LDS dest + inverse-swizzled global src).
// exp2-domain softmax, defer-max, deferred l-reduce, wave-private P buffer.
__global__ __launch_bounds__(512, 4) void attn_kernel(
    const unsigned short* __restrict__ qw,
    const unsigned short* __restrict__ kw,
    const unsigned short* __restrict__ vtw,
    unsigned short* __restrict__ ow)
{
  // LDS: KV double-buffer 2x16KB (K 8KB + V 8KB each), then P 8x4KB
  __shared__ char smem[65536];
  const int tid = threadIdx.x;
  const int w = tid >> 6, lane = tid & 63;
  const int g = lane >> 4, c0 = lane & 15;
  // XCD-aware decode: all 4 q-tiles of one bh on the same XCD
  const int bb = blockIdx.x;                  // 0..511
  const int xcd = bb & 7, slot = bb >> 3;     // slot 0..63
  const int bh = xcd + ((slot >> 2) << 3);    // 0..127
  const int qt = slot & 3;
  const size_t bhoff = (size_t)bh * 1024 * 64;
  const unsigned short* Qb = qw + bhoff;
  const unsigned short* Kb = kw + bhoff;
  const unsigned short* Vb = vtw + bhoff;
  const int q0 = qt * 256 + w * 32;
  char* Pw = smem + 32768 + w * 4096;

  // staging geometry: chunk = tid (0..511); row = chunk>>3, j = chunk&7
  // LDS holds tile with byte swizzle ((row&7)<<4); gload_lds dest is linear,
  // so the global SOURCE is inverse-permuted: j_src = j ^ (row&7).
  const int srow = tid >> 3;
  const int sjx = ((tid & 7) ^ (srow & 7)) << 3;    // element offset in row
  const unsigned short* ksrc = Kb + srow * 64 + sjx;           // + kvt*4096
  const unsigned short* vsrc = Vb + (size_t)srow * 1024 + sjx; // + kv0
  // wave-uniform LDS dest bases (lane*16 added by HW)
  const int wbase = w * 1024;

  // Q as B-operand, hoisted: [qf][chain]  (col=c0 -> q0+qf*16+c0 ; k=d=g*8+j+32i)
  short8v bq[2][2];
  #pragma unroll
  for(int qf = 0; qf < 2; ++qf)
    #pragma unroll
    for(int i = 0; i < 2; ++i)
      bq[qf][i] = *(const short8v*)(Qb + (size_t)(q0 + qf * 16 + c0) * 64 + g * 8 + i * 32);

  floatx4 o[2][4] = {};                 // [qf(=mf)][nf]; row=q=mf*16+g*4+r, col=d=nf*16+c0
  float m_run[2] = {-1e30f, -1e30f};
  float l_part[2] = {0.0f, 0.0f};       // per-thread partial (xor-reduced at end)

  // prologue: stage tile 0 into buffer 0
  gload_lds16(ksrc, smem + wbase);
  gload_lds16(vsrc, smem + 8192 + wbase);
  __syncthreads();

  int cur = 0;
  for(int kv0 = 0; kv0 < 1024; kv0 += 64){
    char* Ksm = smem + cur * 16384;
    char* Vsm = smem + cur * 16384 + 8192;
    // prefetch next tile into alternate buffer
    // (K tile step = 64 rows x 64 elem = 4096 elements; V^T step = 64 columns)
    if(kv0 + 64 < 1024){
      char* alt = smem + (cur ^ 1) * 16384;
      gload_lds16(ksrc + (size_t)(kv0 + 64) * 64, alt + wbase);
      gload_lds16(vsrc + kv0 + 64, alt + 8192 + wbase);
    }
    // S^T tile (64 kv x 32 q), log2-domain: A = K rows from LDS (swizzled read)
    floatx4 st[4][2];
    #pragma unroll
    for(int kf = 0; kf < 4; ++kf){
      const int krow = kf * 16 + c0;
      const char* kr = Ksm + (krow << 7);
      short8v ka0 = *(const short8v*)(kr + (((g    ) ^ (c0 & 7)) << 4));
      short8v ka1 = *(const short8v*)(kr + (((g + 4) ^ (c0 & 7)) << 4));
      #pragma unroll
      for(int qf = 0; qf < 2; ++qf){
        floatx4 z = {};
        z = __builtin_amdgcn_mfma_f32_16x16x32_bf16(ka0, bq[qf][0], z, 0, 0, 0);
        st[kf][qf] = __builtin_amdgcn_mfma_f32_16x16x32_bf16(ka1, bq[qf][1], z, 0, 0, 0);
      }
    }
    // per-q-column max (thread holds 16 kv values per qf; finish via xor 16,32)
    float vmax[2];
    #pragma unroll
    for(int qf = 0; qf < 2; ++qf){
      float vm = -1e30f;
      #pragma unroll
      for(int kf = 0; kf < 4; ++kf)
        #pragma unroll
        for(int r = 0; r < 4; ++r) vm = fmaxf(vm, st[kf][qf][r]);
      vm = fmaxf(vm, __shfl_xor(vm, 16));
      vm = fmaxf(vm, __shfl_xor(vm, 32));
      vmax[qf] = vm;
    }
    // T13 defer-max: only rescale when max grew by > 8 (values bounded by 2^8)
    if(!__all(vmax[0] <= m_run[0] + 8.0f && vmax[1] <= m_run[1] + 8.0f)){
      #pragma unroll
      for(int qf = 0; qf < 2; ++qf){
        float m_new = fmaxf(m_run[qf], vmax[qf]);
        float sc = __builtin_amdgcn_exp2f(m_run[qf] - m_new);
        l_part[qf] *= sc;
        m_run[qf] = m_new;
        float f0 = __shfl(sc, g * 4 + 0);
        float f1 = __shfl(sc, g * 4 + 1);
        float f2 = __shfl(sc, g * 4 + 2);
        float f3 = __shfl(sc, g * 4 + 3);
        #pragma unroll
        for(int nf = 0; nf < 4; ++nf){
          o[qf][nf][0] *= f0; o[qf][nf][1] *= f1; o[qf][nf][2] *= f2; o[qf][nf][3] *= f3;
        }
      }
    }
    // P = exp2(S - m), bf16 pack; per-thread partial row-sums (reduce at end)
    #pragma unroll
    for(int qf = 0; qf < 2; ++qf){
      float ps = 0.0f;
      #pragma unroll
      for(int kf = 0; kf < 4; ++kf){
        ushortx4 pk;
        #pragma unroll
        for(int r = 0; r < 4; ++r){
          float e = __builtin_amdgcn_exp2f(st[kf][qf][r] - m_run[qf]);
          ps += e;
          pk[r] = f2bf(e);
        }
        // P -> LDS [q=qf*16+c0][kv=kf*16+g*4], XOR-swizzled (G4)
        int byo = (qf << 11) + (c0 << 7) + (kf << 5) + (g << 3);
        byo ^= (c0 & 7) << 4;
        *(ushortx4*)(Pw + byo) = pk;
      }
      l_part[qf] += ps;
    }
    // P as A-operand: row=q=mf*16+c0, k=kv=g*8+j(+32i)  (wave-private: no barrier)
    short8v pa[2][2];
    #pragma unroll
    for(int mf = 0; mf < 2; ++mf)
      #pragma unroll
      for(int i = 0; i < 2; ++i){
        int byo = (mf << 11) + (c0 << 7) + (i << 6) + (g << 4);
        byo ^= (c0 & 7) << 4;
        pa[mf][i] = *(const short8v*)(Pw + byo);
      }
    // V^T as B-operand from LDS: row=d=nf*16+c0, k=kv=g*8+j(+32i), swizzled
    #pragma unroll
    for(int nf = 0; nf < 4; ++nf){
      const int vrow = nf * 16 + c0;
      const char* vr = Vsm + (vrow << 7);
      short8v v0 = *(const short8v*)(vr + (((g    ) ^ (c0 & 7)) << 4));
      short8v v1 = *(const short8v*)(vr + (((g + 4) ^ (c0 & 7)) << 4));
      #pragma unroll
      for(int mf = 0; mf < 2; ++mf){
        o[mf][nf] = __builtin_amdgcn_mfma_f32_16x16x32_bf16(pa[mf][0], v0, o[mf][nf], 0, 0, 0);
        o[mf][nf] = __builtin_amdgcn_mfma_f32_16x16x32_bf16(pa[mf][1], v1, o[mf][nf], 0, 0, 0);
      }
    }
    __syncthreads();     // next tile staged (vmcnt drained) + all waves done with cur
    cur ^= 1;
  }

  const int b = bh >> 4, hh = bh & 15;
  #pragma unroll
  for(int mf = 0; mf < 2; ++mf){
    l_part[mf] += __shfl_xor(l_part[mf], 16);
    l_part[mf] += __shfl_xor(l_part[mf], 32);
    float i0 = 1.0f / __shfl(l_part[mf], g * 4 + 0);
    float i1 = 1.0f / __shfl(l_part[mf], g * 4 + 1);
    float i2 = 1.0f / __shfl(l_part[mf], g * 4 + 2);
    float i3 = 1.0f / __shfl(l_part[mf], g * 4 + 3);
    #pragma unroll
    for(int nf = 0; nf < 4; ++nf){
      o[mf][nf][0] *= i0; o[mf][nf][1] *= i1; o[mf][nf][2] *= i2; o[mf][nf][3] *= i3;
      #pragma unroll
      for(int r = 0; r < 4; ++r){
        size_t row = (size_t)b * 1024 + q0 + mf * 16 + g * 4 + r;
        ow[row * 1024 + hh * 64 + nf * 16 + c0] = f2bf(o[mf][nf][r]);
      }
    }
  }
}

// ---- workspace layout (bytes) ----
//   bfT    @ 0         16,777,216   tensor bf16 (8192x1024)
//   bfWq   @ 16777216   6,291,456   w_qkv bf16 (3072x1024)
//   bfWp   @ 23068672   2,097,152   w_proj bf16 (1024x1024)
//   cs     @ 25165824     524,288   RoPE table float2 (1024x64)
//   qw     @ 25690112  16,777,216   Q rope'd*scale bf16 [bh][1024][64]
//   kw     @ 42467328  16,777,216   K rope'd bf16 [bh][1024][64]
//   vtw    @ 59244544  16,777,216   V^T bf16 [bh][64][1024]
//   ow     @ 76021760  16,777,216   attn out bf16 [b*n][c]

extern "C" void kernel_launch(void* const* d_in, const int* in_sizes, int n_in,
                              void* d_out, int out_size, void* d_ws, size_t ws_size,
                              hipStream_t stream){
  const float* tensor = (const float*)d_in[0];
  const float* w_qkv  = (const float*)d_in[1];
  const float* w_proj = (const float*)d_in[2];
  char* ws = (char*)d_ws;
  unsigned short* bfT  = (unsigned short*)(ws);
  unsigned short* bfWq = (unsigned short*)(ws + 16777216);
  unsigned short* bfWp = (unsigned short*)(ws + 23068672);
  float2*         cs   = (float2*)        (ws + 25165824);
  unsigned short* qw   = (unsigned short*)(ws + 25690112);
  unsigned short* kw   = (unsigned short*)(ws + 42467328);
  unsigned short* vtw  = (unsigned short*)(ws + 59244544);
  unsigned short* owp  = (unsigned short*)(ws + 76021760);

  cvt4<<<8192, 256, 0, stream>>>((const floatx4*)tensor, (ushortx4*)bfT, 2097152);
  cvt4<<<3072, 256, 0, stream>>>((const floatx4*)w_qkv,  (ushortx4*)bfWq, 786432);
  cvt4<<<1024, 256, 0, stream>>>((const floatx4*)w_proj, (ushortx4*)bfWp, 262144);
  cs_init<<<256, 256, 0, stream>>>(cs);

  // QKV: M=8192, N=3072, K=1024 ; fused RoPE epilogue
  gemm_bt<1><<<dim3(24, 64), 256, 0, stream>>>(bfT, bfWq, 1024, 3072,
                                               nullptr, cs, qw, kw, vtw);
  // attention: 512 blocks x 512 threads, XCD-swizzled decode inside the kernel
  attn_kernel<<<512, 512, 0, stream>>>(qw, kw, vtw, owp);
  // proj: M=8192, N=1024, K=1024 ; f32 out
  gemm_bt<0><<<dim3(8, 64), 256, 0, stream>>>(owp, bfWp, 1024, 1024,
                                              (float*)d_out, nullptr, nullptr, nullptr, nullptr);
}